// Round 10
// baseline (306.678 us; speedup 1.0000x reference)
//
#include <hip/hip_runtime.h>
#include <hip/hip_bf16.h>

// Problem constants (fixed by reference setup_inputs)
#define BB 4
#define SS 4096
#define DD 1024
#define HH 16
#define HD 64
#define MM (BB * SS)      // 16384
#define KK DD             // 1024
#define NN DD             // 1024

typedef __bf16 bf16x8 __attribute__((ext_vector_type(8)));
typedef float f32x4 __attribute__((ext_vector_type(4)));

typedef __attribute__((address_space(3))) void lds_void_t;
typedef const __attribute__((address_space(1))) void glb_void_t;

// ---------------------------------------------------------------------------
// Fused fp32 -> bf16 conversion, grid-stride (G11: 2048 blocks, 10 iters).
// Regions (in float4 units): x = [0, 2^22); weight w = [2^22 + w*2^18, ...).
// Coverage: 2048*256*10 = 5,242,880 = 2^22 + 4*2^18 exactly.
// ---------------------------------------------------------------------------
__global__ __launch_bounds__(256)
void cvt_all(const float* __restrict__ x,
             const float* __restrict__ wq, const float* __restrict__ wk,
             const float* __restrict__ wv, const float* __restrict__ wo,
             __hip_bfloat16* __restrict__ base)
{
    int idx = blockIdx.x * 256 + threadIdx.x;
    #pragma unroll
    for (int it = 0; it < 10; ++it, idx += 2048 * 256) {
        const float* src;
        __hip_bfloat16* dst;
        int off;
        if (idx < (1 << 22)) {
            src = x; dst = base; off = idx;
        } else {
            const int r = idx - (1 << 22);
            const int w = r >> 18;
            src = (w == 0) ? wq : (w == 1) ? wk : (w == 2) ? wv : wo;
            dst = base + (size_t)(MM * KK) + (size_t)w * (NN * KK);
            off = r & ((1 << 18) - 1);
        }
        float4 v = ((const float4*)src)[off];
        union { __hip_bfloat16 h[4]; uint2 u; } p;
        p.h[0] = __float2bfloat16(v.x);
        p.h[1] = __float2bfloat16(v.y);
        p.h[2] = __float2bfloat16(v.z);
        p.h[3] = __float2bfloat16(v.w);
        ((uint2*)dst)[off] = p.u;
    }
}

// ---------------------------------------------------------------------------
// 256x256-tile, BK=64, 8-wave GEMM — R8 phasing + R9 zero-VALU addressing,
// R10: explicit even/odd K-tile bodies (no runtime-indexed pointer arrays,
// rule #20 safe by construction).
//   C[M,N] = A[M,K] @ B[N,K]^T, K = 1024 (16 K-tiles of 64).
// MODE 0: N=3072 (Wq|Wk|Wv). Q: row-major bf16 + elu+1; K: elu+1 transposed
//         [bh][hd][s] uint2; V: transposed uint2. grid=768.
// MODE 1: N=1024; f32 out row-major. grid=256.
//
// Block swizzle: XCD-pinned A-band (verified R4: FETCH 204->75 MB).
// Addressing: 4 running global pointers (+64 elems per use; row block at
// +65536); 8 loop-invariant LDS read bases with all lane math + swizzle XOR
// folded -> every ds_read/stage is base + compile-time immediate.
// Phasing per K-tile (BIT-IDENTICAL ledger to verified R8):
//   ph0: rd 8B+A0,A1 ; stage A0(kt+1)[kt<15] ; lgkm(8) ; BAR;lgkm(0)+SB ;
//        MFMA(0,1) ; BAR
//   ph1: rd A2,A3 ; stage A1(kt+1)[kt<15] ; BAR;lgkm(0)+SB ; MFMA(2,3) ; BAR
//   ph2: rd A4,A5 ; stage B0(kt+2)[kt<14] ; BAR;lgkm(0)+SB ; MFMA(4,5) ; BAR
//   ph3: rd A6,A7 ; stage B1(kt+2)[kt<14] ; BAR;lgkm(0)+SB ; MFMA(6,7) ;
//        vmcnt(4) [vmcnt(0)@kt=14, none@15] ; BAR
// Stage-target safety: A(kt+1) -> opposite parity (readers done @ kt-1 final
// barrier); B(kt+2) -> same parity (B(kt) reads retired @ ph0 trailing BAR).
// vmcnt FIFO: tile issues 8 loads; vmcnt(4) at tile end completes tile kt+1.
// LDS swizzle: (row,cb) at cb ^ ((row&7)<<4); inverse on global source,
// same XOR folded into read bases. 0 bank conflicts (measured R2+).
// ---------------------------------------------------------------------------
#define STAGE(gp, arr, p, half)                                                  \
    __builtin_amdgcn_global_load_lds((glb_void_t*)(gp),                          \
        (lds_void_t*)(&arr[p][half][(size_t)t * 8]), 16, 0, 0);                  \
    __builtin_amdgcn_global_load_lds((glb_void_t*)(gp + 65536),                  \
        (lds_void_t*)(&arr[p][half][(size_t)(512 + t) * 8]), 16, 0, 0);          \
    gp += 64;

#define MFMA2(i0, i1, va, vb)                                                                         \
    __builtin_amdgcn_s_setprio(1);                                                                    \
    _Pragma("unroll")                                                                                 \
    for (int j = 0; j < 4; ++j) {                                                                     \
        acc[i0][j] = __builtin_amdgcn_mfma_f32_16x16x32_bf16(va[0], bfr[j][0], acc[i0][j], 0, 0, 0);  \
        acc[i0][j] = __builtin_amdgcn_mfma_f32_16x16x32_bf16(va[1], bfr[j][1], acc[i0][j], 0, 0, 0);  \
        acc[i1][j] = __builtin_amdgcn_mfma_f32_16x16x32_bf16(vb[0], bfr[j][0], acc[i1][j], 0, 0, 0);  \
        acc[i1][j] = __builtin_amdgcn_mfma_f32_16x16x32_bf16(vb[1], bfr[j][1], acc[i1][j], 0, 0, 0);  \
    }                                                                                                 \
    __builtin_amdgcn_s_setprio(0);

#define PH_ENTER                                                \
    __builtin_amdgcn_s_barrier();                               \
    asm volatile("s_waitcnt lgkmcnt(0)" ::: "memory");          \
    __builtin_amdgcn_sched_barrier(0);

// One K-tile. AL/AH/BL/BH: this tile's LDS read bases (parity-specific
// named pointers). PN = parity of tile kt+1 (literal); PC = parity of kt.
#define KT_BODY(ktv, AL, AH, BL, BH, PC, PN)                                     \
    {                                                                            \
        bf16x8 bfr[4][2];                                                        \
        bf16x8 x0[2], x1[2];                                                     \
        _Pragma("unroll")                                                        \
        for (int j = 0; j < 4; ++j) {                                            \
            bfr[j][0] = *(const bf16x8*)(BL + j * 2048);                         \
            bfr[j][1] = *(const bf16x8*)(BH + j * 2048);                         \
        }                                                                        \
        x0[0] = *(const bf16x8*)(AL);          x0[1] = *(const bf16x8*)(AH);     \
        x1[0] = *(const bf16x8*)(AL + 2048);   x1[1] = *(const bf16x8*)(AH + 2048); \
        if ((ktv) < 15) { STAGE(gA0, sA, PN, 0); }                               \
        asm volatile("s_waitcnt lgkmcnt(8)" ::: "memory");                       \
        PH_ENTER;                                                                \
        MFMA2(0, 1, x0, x1);                                                     \
        __builtin_amdgcn_s_barrier();                                            \
        x0[0] = *(const bf16x8*)(AL + 2 * 2048); x0[1] = *(const bf16x8*)(AH + 2 * 2048); \
        x1[0] = *(const bf16x8*)(AL + 3 * 2048); x1[1] = *(const bf16x8*)(AH + 3 * 2048); \
        if ((ktv) < 15) { STAGE(gA1, sA, PN, 1); }                               \
        PH_ENTER;                                                                \
        MFMA2(2, 3, x0, x1);                                                     \
        __builtin_amdgcn_s_barrier();                                            \
        x0[0] = *(const bf16x8*)(AL + 4 * 2048); x0[1] = *(const bf16x8*)(AH + 4 * 2048); \
        x1[0] = *(const bf16x8*)(AL + 5 * 2048); x1[1] = *(const bf16x8*)(AH + 5 * 2048); \
        if ((ktv) < 14) { STAGE(gB0, sB, PC, 0); }                               \
        PH_ENTER;                                                                \
        MFMA2(4, 5, x0, x1);                                                     \
        __builtin_amdgcn_s_barrier();                                            \
        x0[0] = *(const bf16x8*)(AL + 6 * 2048); x0[1] = *(const bf16x8*)(AH + 6 * 2048); \
        x1[0] = *(const bf16x8*)(AL + 7 * 2048); x1[1] = *(const bf16x8*)(AH + 7 * 2048); \
        if ((ktv) < 14) { STAGE(gB1, sB, PC, 1); }                               \
        PH_ENTER;                                                                \
        MFMA2(6, 7, x0, x1);                                                     \
        if ((ktv) < 14)       { asm volatile("s_waitcnt vmcnt(4)" ::: "memory"); } \
        else if ((ktv) == 14) { asm volatile("s_waitcnt vmcnt(0)" ::: "memory"); } \
        __builtin_amdgcn_s_barrier();                                            \
    }

template<int MODE>
__global__ __launch_bounds__(512, 2)
void gemm256(const __hip_bfloat16* __restrict__ Ain,
             const __hip_bfloat16* __restrict__ Bin,
             __hip_bfloat16* __restrict__ Obf,
             float* __restrict__ Of32)
{
    __shared__ __align__(16) __hip_bfloat16 sA[2][2][128 * 64];
    __shared__ __align__(16) __hip_bfloat16 sB[2][2][128 * 64];

    // XCD-pinned A-band swizzle.
    const int bid = blockIdx.x;
    const int mt  = ((bid & 7) << 3) | ((bid >> 3) & 7);
    const int nt  = bid >> 6;
    const int m0  = mt << 8;
    const int n0  = nt << 8;

    const int t      = threadIdx.x;
    const int lane   = t & 63;
    const int w      = t >> 6;
    const int warp_m = w >> 2;             // 0..1  -> A half
    const int warp_n = w & 3;              // 0..3
    const int halfB  = warp_n >> 1;        // B half
    const int bn     = (warp_n & 1) << 6;  // 0/64 within B half
    const int lr     = lane & 15;
    const int lq     = lane >> 4;
    const int swz    = (lr & 7) << 4;      // read-side XOR (row&7 == lr&7)

    const int trow = t >> 3;
    const int tcb  = (((t & 7) ^ ((t >> 3) & 7)) << 4);  // inverse-swizzled src col-byte

    // Running global staging pointers (advance +64 elems per use).
    const __hip_bfloat16* gA0 = Ain + (size_t)(m0 +       trow) * 1024 + (tcb >> 1);
    const __hip_bfloat16* gA1 = Ain + (size_t)(m0 + 128 + trow) * 1024 + (tcb >> 1);
    const __hip_bfloat16* gB0 = Bin + (size_t)(n0 +       trow) * 1024 + (tcb >> 1);
    const __hip_bfloat16* gB1 = Bin + (size_t)(n0 + 128 + trow) * 1024 + (tcb >> 1);

    // Loop-invariant LDS read bases (lane math + swizzle folded), named per
    // parity -> no runtime-indexed pointer arrays (rule #20).
    const int aLo = lr * 128 + ((lq * 16) ^ swz);
    const int aHi = lr * 128 + ((64 + lq * 16) ^ swz);
    const int bLo = (bn + lr) * 128 + ((lq * 16) ^ swz);
    const int bHi = (bn + lr) * 128 + ((64 + lq * 16) ^ swz);
    const char* bAlo0 = (const char*)&sA[0][warp_m][0] + aLo;
    const char* bAlo1 = (const char*)&sA[1][warp_m][0] + aLo;
    const char* bAhi0 = (const char*)&sA[0][warp_m][0] + aHi;
    const char* bAhi1 = (const char*)&sA[1][warp_m][0] + aHi;
    const char* bBlo0 = (const char*)&sB[0][halfB][0] + bLo;
    const char* bBlo1 = (const char*)&sB[1][halfB][0] + bLo;
    const char* bBhi0 = (const char*)&sB[0][halfB][0] + bHi;
    const char* bBhi1 = (const char*)&sB[1][halfB][0] + bHi;

    f32x4 acc[8][4];
    #pragma unroll
    for (int i = 0; i < 8; ++i)
        #pragma unroll
        for (int j = 0; j < 4; ++j)
            acc[i][j] = (f32x4){0.f, 0.f, 0.f, 0.f};

    // Prologue: tile0 fully (B0,B1,A0,A1) + B0,B1(tile1) = 12 loads.
    STAGE(gB0, sB, 0, 0); STAGE(gB1, sB, 0, 1);
    STAGE(gA0, sA, 0, 0); STAGE(gA1, sA, 0, 1);
    STAGE(gB0, sB, 1, 0); STAGE(gB1, sB, 1, 1);
    asm volatile("s_waitcnt vmcnt(4)" ::: "memory");   // tile0 resident
    __builtin_amdgcn_s_barrier();

    for (int kt = 0; kt < 16; kt += 2) {
        KT_BODY(kt,     bAlo0, bAhi0, bBlo0, bBhi0, 0, 1);
        KT_BODY(kt + 1, bAlo1, bAhi1, bBlo1, bBhi1, 1, 0);
    }

    // Epilogue. C/D layout: col = lr, row = lq*4 + reg (4 consecutive rows).
    if constexpr (MODE == 0) {
        const int wsel = n0 >> 10;                       // 0:Q 1:K 2:V (uniform per block)
        const int nb   = n0 & 1023;
        __hip_bfloat16* Op = Obf + (size_t)wsel * ((size_t)MM * KK);
        if (wsel == 0) {
            #pragma unroll
            for (int i = 0; i < 8; ++i)
                #pragma unroll
                for (int j = 0; j < 4; ++j)
                    #pragma unroll
                    for (int r = 0; r < 4; ++r) {
                        const int row = m0 + warp_m * 128 + i * 16 + lq * 4 + r;
                        const int col = nb + warp_n * 64 + j * 16 + lr;
                        float v = acc[i][j][r];
                        v = (v > 0.f) ? v + 1.f : __expf(v);
                        Op[(size_t)row * 1024 + col] = __float2bfloat16(v);
                    }
        } else {
            // K (elu) / V: transposed [bh][hd][s], packed 4-bf16 stores.
            const bool doelu = (wsel == 1);
            #pragma unroll
            for (int i = 0; i < 8; ++i)
                #pragma unroll
                for (int j = 0; j < 4; ++j) {
                    const int row0 = m0 + warp_m * 128 + i * 16 + lq * 4;  // s base
                    const int col  = nb + warp_n * 64 + j * 16 + lr;       // h*64+hd
                    const int b    = row0 >> 12;
                    const int s    = row0 & 4095;
                    union { __hip_bfloat16 hh[4]; uint2 u; } pk;
                    #pragma unroll
                    for (int r = 0; r < 4; ++r) {
                        float v = acc[i][j][r];
                        if (doelu) v = (v > 0.f) ? v + 1.f : __expf(v);
                        pk.hh[r] = __float2bfloat16(v);
                    }
                    *(uint2*)(Op + ((size_t)((b * 16 + (col >> 6)) * 64 + (col & 63)) * 4096 + s)) = pk.u;
                }
        }
    } else {
        #pragma unroll
        for (int i = 0; i < 8; ++i)
            #pragma unroll
            for (int j = 0; j < 4; ++j)
                #pragma unroll
                for (int r = 0; r < 4; ++r) {
                    const int row = m0 + warp_m * 128 + i * 16 + lq * 4 + r;
                    const int col = n0 + warp_n * 64 + j * 16 + lr;
                    Of32[(size_t)row * 1024 + col] = acc[i][j][r];
                }
    }
}

// ---------------------------------------------------------------------------
// KV + k_sum partials from TRANSPOSED K/V (unchanged — verified R6)
// ---------------------------------------------------------------------------
#define KV_SPLIT 8
__global__ __launch_bounds__(256)
void kv_gemm(const __hip_bfloat16* __restrict__ KB,
             const __hip_bfloat16* __restrict__ VB,
             float* __restrict__ KVp)
{
    __shared__ float sRed[65 * 66];

    const int bh = blockIdx.x;
    const int sp = blockIdx.y;
    const int t  = threadIdx.x;
    const int lane = t & 63;
    const int wv = t >> 6;
    const int lr = lane & 15;
    const int lq = lane >> 4;

    const __hip_bfloat16* kbase = KB + (size_t)bh * 64 * 4096;
    const __hip_bfloat16* vbase = VB + (size_t)bh * 64 * 4096;
    const int k0w = sp * 512 + wv * 128 + lq * 8;

    f32x4 acc[4][4];
    f32x4 ksacc[4];
    #pragma unroll
    for (int i = 0; i < 4; i++) {
        ksacc[i] = (f32x4){0.f, 0.f, 0.f, 0.f};
        #pragma unroll
        for (int j = 0; j < 4; j++)
            acc[i][j] = (f32x4){0.f, 0.f, 0.f, 0.f};
    }

    bf16x8 ones;
    #pragma unroll
    for (int j = 0; j < 8; j++) ones[j] = (__bf16)1.0f;

    #pragma unroll
    for (int c = 0; c < 4; ++c) {
        const int k0 = k0w + c * 32;
        bf16x8 ak[4], bv[4];
        #pragma unroll
        for (int i = 0; i < 4; ++i) {
            ak[i] = *(const bf16x8*)(kbase + (size_t)(i * 16 + lr) * 4096 + k0);
            bv[i] = *(const bf16x8*)(vbase + (size_t)(i * 16 + lr) * 4096 + k0);
        }
        #pragma unroll
        for (int i = 0; i < 4; ++i) {
            #pragma unroll
            for (int j = 0; j < 4; ++j)
                acc[i][j] = __builtin_amdgcn_mfma_f32_16x16x32_bf16(ak[i], bv[j], acc[i][j], 0, 0, 0);
            ksacc[i] = __builtin_amdgcn_mfma_f32_16x16x32_bf16(ak[i], ones, ksacc[i], 0, 0, 0);
        }
    }

    for (int w = 0; w < 4; w++) {
        if (wv == w) {
            #pragma unroll
            for (int i = 0; i < 4; i++) {
                #pragma unroll
                for (int j = 0; j < 4; j++) {
                    float* p = &sRed[(j * 16 + lr) * 66 + i * 16 + lq * 4];
                    if (w == 0) {
                        #pragma unroll
                        for (int r = 0; r < 4; r++) p[r] = acc[i][j][r];
                    } else {
                        #pragma unroll
                        for (int r = 0; r < 4; r++) p[r] += acc[i][j][r];
                    }
                }
                if (lr == 0) {
                    float* p = &sRed[64 * 66 + i * 16 + lq * 4];
                    if (w == 0) {
                        #pragma unroll
                        for (int r = 0; r < 4; r++) p[r] = ksacc[i][r];
                    } else {
                        #pragma unroll
                        for (int r = 0; r < 4; r++) p[r] += ksacc[i][r];
                    }
                }
            }
        }
        __syncthreads();
    }

    float* outp = KVp + (size_t)(sp * 64 + bh) * (65 * 64);
    #pragma unroll
    for (int i = 0; i < 17; i++) {
        int idx = i * 256 + t;
        if (idx < 65 * 64) {
            int e = idx >> 6, d = idx & 63;
            outp[idx] = sRed[e * 66 + d];
        }
    }
}

// ---------------------------------------------------------------------------
// Reduce partials -> KVt + KS (wide, verified R8)
// ---------------------------------------------------------------------------
__global__ __launch_bounds__(256)
void kv_reduce(const float* __restrict__ KVp,
               __hip_bfloat16* __restrict__ KVt,
               float* __restrict__ KS)
{
    const int bh = blockIdx.x;
    const int q  = blockIdx.y;     // 0..3
    const int t  = threadIdx.x;
    #pragma unroll
    for (int i = 0; i < 4; i++) {
        int idx = q * 1024 + i * 256 + t;
        float s = 0.f;
        #pragma unroll
        for (int sp = 0; sp < KV_SPLIT; sp++)
            s += KVp[((size_t)(sp * 64 + bh) * 65) * 64 + idx];
        KVt[(size_t)bh * 4096 + idx] = __float2bfloat16(s);
    }
    if (q == 0 && t < 64) {
        float s = 0.f;
        #pragma unroll
        for (int sp = 0; sp < KV_SPLIT; sp++)
            s += KVp[((size_t)(sp * 64 + bh) * 65 + 64) * 64 + t];
        KS[bh * 64 + t] = s;
    }
}

// ---------------------------------------------------------------------------
// MFMA attention apply (unchanged — verified)
// ---------------------------------------------------------------------------
__global__ __launch_bounds__(256)
void attn_mfma(const __hip_bfloat16* __restrict__ Q,
               const __hip_bfloat16* __restrict__ KVt,
               const float* __restrict__ KS,
               __hip_bfloat16* __restrict__ O)
{
    const int bh = blockIdx.x;
    const int b  = bh >> 4;
    const int h  = bh & 15;
    const int s0 = blockIdx.y * 128;
    const int t  = threadIdx.x;
    const int lane = t & 63;
    const int wv = t >> 6;

    __shared__ __align__(16) __hip_bfloat16 sQ[128][72];
    __shared__ __align__(16) __hip_bfloat16 sKVt[64][72];
    __shared__ float sKS[64];
    __shared__ float sZ[128];

    {
        const float4* kvp = (const float4*)(KVt + (size_t)bh * 4096);
        #pragma unroll
        for (int i = 0; i < 2; i++) {
            int c = i * 256 + t;
            *(float4*)(&sKVt[c >> 3][(c & 7) * 8]) = kvp[c];
        }
        if (t < 64) sKS[t] = KS[bh * 64 + t];
    }
    {
        const __hip_bfloat16* qp = Q + ((size_t)b * SS + s0) * DD + h * HD;
        int r  = t >> 1;
        int c0 = (t & 1) * 32;
        #pragma unroll
        for (int i = 0; i < 32; i += 8)
            *(float4*)(&sQ[r][c0 + i]) = *(const float4*)(qp + (size_t)r * DD + c0 + i);
    }
    __syncthreads();

    if (t < 128) {
        float z = 0.f;
        #pragma unroll
        for (int d8 = 0; d8 < 64; d8 += 8) {
            bf16x8 qv = *(const bf16x8*)(&sQ[t][d8]);
            #pragma unroll
            for (int j = 0; j < 8; j++) z += (float)qv[j] * sKS[d8 + j];
        }
        sZ[t] = 1.f / (z + 1e-6f);
    }

    const int lr = lane & 15;
    const int lq = lane >> 4;
    f32x4 acc[2][4];
    #pragma unroll
    for (int i = 0; i < 2; i++)
        #pragma unroll
        for (int j = 0; j < 4; j++)
            acc[i][j] = (f32x4){0.f, 0.f, 0.f, 0.f};

    bf16x8 af[2][2], bfv[4][2];
    #pragma unroll
    for (int ks = 0; ks < 2; ks++) {
        #pragma unroll
        for (int i = 0; i < 2; i++)
            af[i][ks] = *(const bf16x8*)(&sQ[wv * 32 + i * 16 + lr][lq * 8 + ks * 32]);
        #pragma unroll
        for (int j = 0; j < 4; j++)
            bfv[j][ks] = *(const bf16x8*)(&sKVt[j * 16 + lr][lq * 8 + ks * 32]);
    }
    #pragma unroll
    for (int i = 0; i < 2; i++)
        #pragma unroll
        for (int j = 0; j < 4; j++) {
            acc[i][j] = __builtin_amdgcn_mfma_f32_16x16x32_bf16(af[i][0], bfv[j][0], acc[i][j], 0, 0, 0);
            acc[i][j] = __builtin_amdgcn_mfma_f32_16x16x32_bf16(af[i][1], bfv[j][1], acc[i][j], 0, 0, 0);
        }
    __syncthreads();

    __hip_bfloat16* op = O + ((size_t)b * SS + s0) * DD + h * HD;
    #pragma unroll
    for (int i = 0; i < 2; i++)
        #pragma unroll
        for (int j = 0; j < 4; j++)
            #pragma unroll
            for (int r = 0; r < 4; r++) {
                int row = wv * 32 + i * 16 + lq * 4 + r;
                int col = j * 16 + lr;
                op[(size_t)row * DD + col] = __float2bfloat16(acc[i][j][r] * sZ[row]);
            }
}

// ---------------------------------------------------------------------------
// launch
// ---------------------------------------------------------------------------
extern "C" void kernel_launch(void* const* d_in, const int* in_sizes, int n_in,
                              void* d_out, int out_size, void* d_ws, size_t ws_size,
                              hipStream_t stream) {
    const float* x  = (const float*)d_in[0];
    const float* Wq = (const float*)d_in[1];
    const float* Wk = (const float*)d_in[2];
    const float* Wv = (const float*)d_in[3];
    const float* Wo = (const float*)d_in[4];
    float* out = (float*)d_out;

    char* ws = (char*)d_ws;
    const size_t XB_BYTES = (size_t)MM * KK * 2;   // 32MB
    const size_t WB_BYTES = (size_t)NN * KK * 2;   // 2MB
    __hip_bfloat16* xb  = (__hip_bfloat16*)(ws);
    __hip_bfloat16* wqb = (__hip_bfloat16*)(ws + XB_BYTES);
    __hip_bfloat16* wob = (__hip_bfloat16*)(ws + XB_BYTES + 3 * WB_BYTES);
    __hip_bfloat16* qb  = (__hip_bfloat16*)(ws + XB_BYTES + 4 * WB_BYTES);
    __hip_bfloat16* kb  = (__hip_bfloat16*)(ws + 2 * XB_BYTES + 4 * WB_BYTES);  // K^T [bh][d][s]
    __hip_bfloat16* vb  = (__hip_bfloat16*)(ws + 3 * XB_BYTES + 4 * WB_BYTES);  // V^T [bh][d][s]
    __hip_bfloat16* KVt = (__hip_bfloat16*)(ws + 4 * XB_BYTES + 4 * WB_BYTES);          // 512KB
    float*          KS  = (float*)(ws + 4 * XB_BYTES + 4 * WB_BYTES + 524288);          // 16KB
    // KV partials (8.3MB f32) overlay xb (dead after QKV GEMM; attn writes
    // ab=xb only after kv_reduce). Stream-ordered, safe.
    float* KVp = (float*)(ws);
    __hip_bfloat16* ab = xb;

    // 1. convert ALL inputs to bf16, grid-stride (G11)
    cvt_all<<<2048, 256, 0, stream>>>(x, Wq, Wk, Wv, Wo, xb);

    // 2. fused QKV projection: [16384,1024] @ [3072,1024]^T.
    //    Q -> qb row-major (+elu); K,V -> kb,vb TRANSPOSED [bh][d][s].
    gemm256<0><<<768, 512, 0, stream>>>(xb, wqb, qb, nullptr);

    // 3. KV + k_sum partials (B^T GEMM on transposed K/V), then reduce (wide)
    kv_gemm<<<dim3(BB * HH, KV_SPLIT), 256, 0, stream>>>(kb, vb, KVp);
    kv_reduce<<<dim3(BB * HH, 4), 256, 0, stream>>>(KVp, KVt, KS);

    // 4. attention output (normalized), bf16, MFMA
    attn_mfma<<<dim3(BB * HH, SS / 128), 256, 0, stream>>>(qb, KVt, KS, ab);

    // 5. final projection -> fp32 d_out
    gemm256<1><<<256, 512, 0, stream>>>(ab, wob, nullptr, out);
}